// Round 1
// baseline (293.316 us; speedup 1.0000x reference)
//
#include <hip/hip_runtime.h>

typedef __attribute__((ext_vector_type(4))) float f32x4;
typedef __attribute__((ext_vector_type(8))) short s16x8;

#define NTOK 65536

__device__ __forceinline__ unsigned short f2b(float f) {
    unsigned int u = __float_as_uint(f);
    u = (u + 0x7FFFu + ((u >> 16) & 1u)) >> 16;
    return (unsigned short)u;
}
__device__ __forceinline__ float b2f(unsigned short h) {
    return __uint_as_float(((unsigned int)h) << 16);
}

// ---------------- P1: weight prep (fold ia3, cast to bf16, zero counters) ---
__global__ __launch_bounds__(256) void prep_kernel(
    const float* __restrict__ Wb, const float* __restrict__ bb,
    const float* __restrict__ B, const float* __restrict__ ia3,
    const float* __restrict__ We,
    unsigned short* __restrict__ WbP, unsigned short* __restrict__ WeP,
    float* __restrict__ bbP, float* __restrict__ BP, int* __restrict__ cnt)
{
    int i = blockIdx.x * 256 + threadIdx.x;
    if (i < 4) cnt[i] = 0;
    if (i < 512) bbP[i] = bb[i] * ia3[i];
    if (i < 8 * 512) BP[i] = B[i] * 4.0f * ia3[i & 511];          // ALPHA/RANK = 4
    if (i < 512 * 512) WbP[i] = f2b(Wb[i] * ia3[i >> 9]);         // row o = i>>9
    if (i < 4 * 512 * 512) WeP[i] = f2b(We[i]);
}

// ---------------- P2: router + LoRA-t + expert compaction -------------------
// one wave per token (16 tokens per wave, 64 per block); Wr/A k-slices in regs
__global__ __launch_bounds__(256) void router_kernel(
    const float* __restrict__ x, const float* __restrict__ A,
    const float* __restrict__ Wr, const float* __restrict__ br,
    float* __restrict__ wgt, float* __restrict__ tws,
    int* __restrict__ perm, int* __restrict__ cnt)
{
    __shared__ int sCnt[4];
    __shared__ int sBase[4];
    __shared__ int sE[64];
    __shared__ int sPos[64];

    const int tid = threadIdx.x;
    const int wave = tid >> 6, lane = tid & 63;
    const int k0 = lane * 8;

    f32x4 wrv[4][2];
#pragma unroll
    for (int e = 0; e < 4; ++e) {
        wrv[e][0] = *(const f32x4*)(Wr + e * 512 + k0);
        wrv[e][1] = *(const f32x4*)(Wr + e * 512 + k0 + 4);
    }
    f32x4 av[8][2];
#pragma unroll
    for (int j = 0; j < 8; ++j) {
        av[j][0] = *(const f32x4*)(A + (size_t)(k0 + j) * 8);
        av[j][1] = *(const f32x4*)(A + (size_t)(k0 + j) * 8 + 4);
    }
    const float br0 = br[0], br1 = br[1], br2 = br[2], br3 = br[3];

    if (tid < 4) sCnt[tid] = 0;
    __syncthreads();

    const int tok0 = blockIdx.x * 64 + wave * 16;
    for (int it = 0; it < 16; ++it) {
        const int tok = tok0 + it;
        const float* xr = x + (size_t)tok * 512 + k0;
        f32x4 x0 = *(const f32x4*)xr;
        f32x4 x1 = *(const f32x4*)(xr + 4);
        float ar[4] = {0.f, 0.f, 0.f, 0.f};
        float at[8] = {0.f, 0.f, 0.f, 0.f, 0.f, 0.f, 0.f, 0.f};
#pragma unroll
        for (int j = 0; j < 8; ++j) {
            const float xv = (j < 4) ? x0[j] : x1[j - 4];
#pragma unroll
            for (int e = 0; e < 4; ++e) ar[e] += xv * wrv[e][j >> 2][j & 3];
#pragma unroll
            for (int r = 0; r < 8; ++r) at[r] += xv * av[j][r >> 2][r & 3];
        }
#pragma unroll
        for (int off = 32; off >= 1; off >>= 1) {
#pragma unroll
            for (int e = 0; e < 4; ++e) ar[e] += __shfl_xor(ar[e], off);
#pragma unroll
            for (int r = 0; r < 8; ++r) at[r] += __shfl_xor(at[r], off);
        }
        if (lane == 0) {
            const float l0 = ar[0] + br0, l1 = ar[1] + br1;
            const float l2 = ar[2] + br2, l3 = ar[3] + br3;
            int e = 0; float m = l0;
            if (l1 > m) { m = l1; e = 1; }
            if (l2 > m) { m = l2; e = 2; }
            if (l3 > m) { m = l3; e = 3; }
            const float s = expf(l0 - m) + expf(l1 - m) + expf(l2 - m) + expf(l3 - m);
            wgt[tok] = 1.0f / s;  // top value is exp(0)=1
            float* tp = tws + (size_t)tok * 8;
#pragma unroll
            for (int r = 0; r < 8; ++r) tp[r] = at[r];
            const int slot = wave * 16 + it;
            sE[slot] = e;
            sPos[slot] = atomicAdd(&sCnt[e], 1);
        }
    }
    __syncthreads();
    if (tid < 4) sBase[tid] = atomicAdd(&cnt[tid], sCnt[tid]);
    __syncthreads();
    if (tid < 64) {
        const int e = sE[tid];
        perm[e * NTOK + sBase[e] + sPos[tid]] = blockIdx.x * 64 + tid;
    }
}

// ---------------- P3: grouped GEMM (base + top-1 expert, fused epilogue) ----
// 64 gathered tokens/block; 8 waves x 64 out-cols; each wave does Wb AND We[e]
__global__ __launch_bounds__(512) void main_kernel(
    const float* __restrict__ x,
    const unsigned short* __restrict__ WbP, const unsigned short* __restrict__ WeP,
    const float* __restrict__ bbP, const float* __restrict__ BP,
    const float* __restrict__ be,
    const float* __restrict__ wgt, const float* __restrict__ tws,
    const int* __restrict__ perm, const int* __restrict__ cnt,
    float* __restrict__ out)
{
    __shared__ unsigned short sX[64 * 512];  // 64KB, XOR-swizzled bf16 x-tile

    const int e = blockIdx.x >> 10;
    const int ti = blockIdx.x & 1023;
    const int n = cnt[e];
    const int base = ti * 64;
    if (base >= n) return;
    const int mcount = min(64, n - base);

    const int tid = threadIdx.x;

    // ---- stage x tile: f32 -> bf16, swizzle byte ^= (row&7)<<4 ----
    {
        const int row = tid >> 3, seg = tid & 7;
        if (row < mcount) {
            const int tok = perm[e * NTOK + base + row];
            const float* xr = x + (size_t)tok * 512 + seg * 64;
#pragma unroll
            for (int c8 = 0; c8 < 8; ++c8) {
                f32x4 v0 = *(const f32x4*)(xr + c8 * 8);
                f32x4 v1 = *(const f32x4*)(xr + c8 * 8 + 4);
                s16x8 hv;
#pragma unroll
                for (int j = 0; j < 4; ++j) {
                    hv[j]     = (short)f2b(v0[j]);
                    hv[j + 4] = (short)f2b(v1[j]);
                }
                const int byteoff = (row * 1024 + seg * 128 + c8 * 16) ^ ((row & 7) << 4);
                *(s16x8*)((char*)sX + byteoff) = hv;
            }
        }
    }
    __syncthreads();

    const int wave = tid >> 6, lane = tid & 63;
    const int lanelo = lane & 15;
    const int akoff = (lane >> 4) * 8;       // k sub-block of the MFMA fragment
    const int colBase = wave * 64;           // this wave's 64 output columns

    f32x4 accB[4][4], accE[4][4];
#pragma unroll
    for (int mb = 0; mb < 4; ++mb)
#pragma unroll
        for (int nb = 0; nb < 4; ++nb) {
            accB[mb][nb] = (f32x4){0.f, 0.f, 0.f, 0.f};
            accE[mb][nb] = (f32x4){0.f, 0.f, 0.f, 0.f};
        }

    const unsigned short* wbRow = WbP + (size_t)(colBase + lanelo) * 512 + akoff;
    const unsigned short* weRow = WeP + (size_t)e * 512 * 512 + (size_t)(colBase + lanelo) * 512 + akoff;

#pragma unroll 2
    for (int kk = 0; kk < 16; ++kk) {
        s16x8 a[4];
#pragma unroll
        for (int mb = 0; mb < 4; ++mb) {
            const int row = mb * 16 + lanelo;
            const int byteoff = (row * 1024 + (kk * 32 + akoff) * 2) ^ ((row & 7) << 4);
            a[mb] = *(const s16x8*)((const char*)sX + byteoff);
        }
#pragma unroll
        for (int nb = 0; nb < 4; ++nb) {
            const s16x8 bB = *(const s16x8*)(wbRow + (size_t)nb * 16 * 512 + kk * 32);
            const s16x8 bE = *(const s16x8*)(weRow + (size_t)nb * 16 * 512 + kk * 32);
#pragma unroll
            for (int mb = 0; mb < 4; ++mb) {
                accB[mb][nb] = __builtin_amdgcn_mfma_f32_16x16x32_bf16(a[mb], bB, accB[mb][nb], 0, 0, 0);
                accE[mb][nb] = __builtin_amdgcn_mfma_f32_16x16x32_bf16(a[mb], bE, accE[mb][nb], 0, 0, 0);
            }
        }
    }

    // ---- epilogue: out = accB + bb' + t.B' + w*(accE + be[e]) ----
    float bbv[4], bev[4], bp[8][4];
#pragma unroll
    for (int nb = 0; nb < 4; ++nb) {
        const int o = colBase + nb * 16 + lanelo;
        bbv[nb] = bbP[o];
        bev[nb] = be[e * 512 + o];
#pragma unroll
        for (int j = 0; j < 8; ++j) bp[j][nb] = BP[j * 512 + o];
    }

#pragma unroll
    for (int mb = 0; mb < 4; ++mb) {
#pragma unroll
        for (int r = 0; r < 4; ++r) {
            const int trow = mb * 16 + (lane >> 4) * 4 + r;
            if (trow < mcount) {
                const int tok = perm[e * NTOK + base + trow];
                const float wv = wgt[tok];
                const f32x4 t0 = *(const f32x4*)(tws + (size_t)tok * 8);
                const f32x4 t1 = *(const f32x4*)(tws + (size_t)tok * 8 + 4);
                float* orow = out + (size_t)tok * 512 + colBase + lanelo;
#pragma unroll
                for (int nb = 0; nb < 4; ++nb) {
                    float lora = 0.f;
#pragma unroll
                    for (int j = 0; j < 4; ++j) lora += t0[j] * bp[j][nb];
#pragma unroll
                    for (int j = 0; j < 4; ++j) lora += t1[j] * bp[j + 4][nb];
                    const float v = accB[mb][nb][r] + bbv[nb] + lora
                                  + wv * (accE[mb][nb][r] + bev[nb]);
                    orow[nb * 16] = v;
                }
            }
        }
    }
}

extern "C" void kernel_launch(void* const* d_in, const int* in_sizes, int n_in,
                              void* d_out, int out_size, void* d_ws, size_t ws_size,
                              hipStream_t stream)
{
    const float* x   = (const float*)d_in[0];
    const float* Wb  = (const float*)d_in[1];
    const float* bb  = (const float*)d_in[2];
    const float* A   = (const float*)d_in[3];
    const float* B   = (const float*)d_in[4];
    const float* ia3 = (const float*)d_in[5];
    const float* Wr  = (const float*)d_in[6];
    const float* br  = (const float*)d_in[7];
    const float* We  = (const float*)d_in[8];
    const float* be  = (const float*)d_in[9];
    float* out = (float*)d_out;

    char* w = (char*)d_ws;
    int* cnt            = (int*)w;                              // 256 B
    unsigned short* WbP = (unsigned short*)(w + 256);           // 512*512*2
    unsigned short* WeP = (unsigned short*)(w + 256 + 524288);  // 4*512*512*2
    float* bbP          = (float*)(w + 2621696);                // 512*4
    float* BP           = (float*)(w + 2623744);                // 8*512*4 (pad)
    float* wgt          = (float*)(w + 2640128);                // 65536*4
    float* tws          = (float*)(w + 2902272);                // 65536*8*4
    int* perm           = (int*)(w + 4999424);                  // 4*65536*4

    hipLaunchKernelGGL(prep_kernel, dim3(4096), dim3(256), 0, stream,
                       Wb, bb, B, ia3, We, WbP, WeP, bbP, BP, cnt);
    hipLaunchKernelGGL(router_kernel, dim3(1024), dim3(256), 0, stream,
                       x, A, Wr, br, wgt, tws, perm, cnt);
    hipLaunchKernelGGL(main_kernel, dim3(4096), dim3(512), 0, stream,
                       x, WbP, WeP, bbP, BP, be, wgt, tws, perm, cnt, out);
}

// Round 2
// 283.289 us; speedup vs baseline: 1.0354x; 1.0354x over previous
//
#include <hip/hip_runtime.h>

typedef __attribute__((ext_vector_type(4))) float f32x4;
typedef __attribute__((ext_vector_type(8))) short s16x8;

#define NTOK 65536

__device__ __forceinline__ unsigned short f2b(float f) {
    unsigned int u = __float_as_uint(f);
    u = (u + 0x7FFFu + ((u >> 16) & 1u)) >> 16;
    return (unsigned short)u;
}

// ---------------- P1: weight prep (fold ia3, cast to bf16, zero counters) ---
__global__ __launch_bounds__(256) void prep_kernel(
    const float* __restrict__ Wb, const float* __restrict__ bb,
    const float* __restrict__ B, const float* __restrict__ ia3,
    const float* __restrict__ We,
    unsigned short* __restrict__ WbP, unsigned short* __restrict__ WeP,
    float* __restrict__ bbP, float* __restrict__ BP, int* __restrict__ cnt)
{
    int i = blockIdx.x * 256 + threadIdx.x;
    if (i < 4) cnt[i] = 0;
    if (i < 512) bbP[i] = bb[i] * ia3[i];
    if (i < 8 * 512) BP[i] = B[i] * 4.0f * ia3[i & 511];          // ALPHA/RANK = 4
    if (i < 512 * 512) WbP[i] = f2b(Wb[i] * ia3[i >> 9]);         // row o = i>>9
    if (i < 4 * 512 * 512) WeP[i] = f2b(We[i]);
}

// ---------------- P2: router + LoRA-t + expert compaction -------------------
__global__ __launch_bounds__(256) void router_kernel(
    const float* __restrict__ x, const float* __restrict__ A,
    const float* __restrict__ Wr, const float* __restrict__ br,
    float* __restrict__ wgt, float* __restrict__ tws,
    int* __restrict__ perm, int* __restrict__ cnt)
{
    __shared__ int sCnt[4];
    __shared__ int sBase[4];
    __shared__ int sE[64];
    __shared__ int sPos[64];

    const int tid = threadIdx.x;
    const int wave = tid >> 6, lane = tid & 63;
    const int k0 = lane * 8;

    f32x4 wrv[4][2];
#pragma unroll
    for (int e = 0; e < 4; ++e) {
        wrv[e][0] = *(const f32x4*)(Wr + e * 512 + k0);
        wrv[e][1] = *(const f32x4*)(Wr + e * 512 + k0 + 4);
    }
    f32x4 av[8][2];
#pragma unroll
    for (int j = 0; j < 8; ++j) {
        av[j][0] = *(const f32x4*)(A + (size_t)(k0 + j) * 8);
        av[j][1] = *(const f32x4*)(A + (size_t)(k0 + j) * 8 + 4);
    }
    const float br0 = br[0], br1 = br[1], br2 = br[2], br3 = br[3];

    if (tid < 4) sCnt[tid] = 0;
    __syncthreads();

    const int tok0 = blockIdx.x * 64 + wave * 16;
    for (int it = 0; it < 16; ++it) {
        const int tok = tok0 + it;
        const float* xr = x + (size_t)tok * 512 + k0;
        f32x4 x0 = *(const f32x4*)xr;
        f32x4 x1 = *(const f32x4*)(xr + 4);
        float ar[4] = {0.f, 0.f, 0.f, 0.f};
        float at[8] = {0.f, 0.f, 0.f, 0.f, 0.f, 0.f, 0.f, 0.f};
#pragma unroll
        for (int j = 0; j < 8; ++j) {
            const float xv = (j < 4) ? x0[j] : x1[j - 4];
#pragma unroll
            for (int e = 0; e < 4; ++e) ar[e] += xv * wrv[e][j >> 2][j & 3];
#pragma unroll
            for (int r = 0; r < 8; ++r) at[r] += xv * av[j][r >> 2][r & 3];
        }
#pragma unroll
        for (int off = 32; off >= 1; off >>= 1) {
#pragma unroll
            for (int e = 0; e < 4; ++e) ar[e] += __shfl_xor(ar[e], off);
#pragma unroll
            for (int r = 0; r < 8; ++r) at[r] += __shfl_xor(at[r], off);
        }
        if (lane == 0) {
            const float l0 = ar[0] + br0, l1 = ar[1] + br1;
            const float l2 = ar[2] + br2, l3 = ar[3] + br3;
            int e = 0; float m = l0;
            if (l1 > m) { m = l1; e = 1; }
            if (l2 > m) { m = l2; e = 2; }
            if (l3 > m) { m = l3; e = 3; }
            const float s = expf(l0 - m) + expf(l1 - m) + expf(l2 - m) + expf(l3 - m);
            wgt[tok] = 1.0f / s;  // top value is exp(0)=1
            float* tp = tws + (size_t)tok * 8;
#pragma unroll
            for (int r = 0; r < 8; ++r) tp[r] = at[r];
            const int slot = wave * 16 + it;
            sE[slot] = e;
            sPos[slot] = atomicAdd(&sCnt[e], 1);
        }
    }
    __syncthreads();
    if (tid < 4) sBase[tid] = atomicAdd(&cnt[tid], sCnt[tid]);
    __syncthreads();
    if (tid < 64) {
        const int e = sE[tid];
        perm[e * NTOK + sBase[e] + sPos[tid]] = blockIdx.x * 64 + tid;
    }
}

// ---------------- P3: grouped GEMM, 16 waves, K-chunked double-buffer -------
// block: 64 gathered tokens x 512 cols x {Wb, We[e]}; wave-tile 64r x 32c both
// mats -> acc 64 regs; 1024 threads forces <=128 regs -> 4 waves/SIMD resident
__global__ __launch_bounds__(1024) void main_kernel(
    const float* __restrict__ x,
    const unsigned short* __restrict__ WbP, const unsigned short* __restrict__ WeP,
    const float* __restrict__ bbP, const float* __restrict__ BP,
    const float* __restrict__ be,
    const float* __restrict__ wgt, const float* __restrict__ tws,
    const int* __restrict__ perm, const int* __restrict__ cnt,
    float* __restrict__ out)
{
    __shared__ unsigned short sX[2][64 * 128];  // 2 x 16KB K-chunks, swizzled

    const int e = blockIdx.x >> 10;
    const int ti = blockIdx.x & 1023;
    const int n = cnt[e];
    const int base = ti * 64;
    if (base >= n) return;
    const int mcount = min(64, n - base);

    const int tid = threadIdx.x;
    const int lane = tid & 63;
    const int wave = tid >> 6;
    const int lanelo = lane & 15;
    const int g = lane >> 4;

    // ---- staging assignment: thread -> (row, 16B-granule) of the K-chunk ----
    const int srow = tid >> 4;          // 0..63
    const int sgran = tid & 15;         // 0..15 (8 f32 / 16B-bf16 each)
    const int sIdx = base + min(srow, mcount - 1);
    const int stok = perm[e * NTOK + sIdx];
    const float* sSrc = x + (size_t)stok * 512 + sgran * 8;
    const int sDstByte = srow * 256 + ((sgran ^ (srow & 7)) << 4);

    // prologue: stage chunk 0
    {
        f32x4 v0 = *(const f32x4*)sSrc;
        f32x4 v1 = *(const f32x4*)(sSrc + 4);
        s16x8 hv;
#pragma unroll
        for (int j = 0; j < 4; ++j) { hv[j] = (short)f2b(v0[j]); hv[j + 4] = (short)f2b(v1[j]); }
        *(s16x8*)((char*)sX[0] + sDstByte) = hv;
    }
    __syncthreads();

    const int colBase = wave * 32;
    f32x4 accB[4][2], accE[4][2];
#pragma unroll
    for (int mb = 0; mb < 4; ++mb)
#pragma unroll
        for (int nb = 0; nb < 2; ++nb) {
            accB[mb][nb] = (f32x4){0.f, 0.f, 0.f, 0.f};
            accE[mb][nb] = (f32x4){0.f, 0.f, 0.f, 0.f};
        }

    const unsigned short* wbRow = WbP + (size_t)(colBase + lanelo) * 512 + g * 8;
    const unsigned short* weRow = WeP + ((size_t)e << 18) + (size_t)(colBase + lanelo) * 512 + g * 8;

    for (int c = 0; c < 4; ++c) {
        // T14: issue next chunk's global loads before compute
        f32x4 p0, p1;
        if (c < 3) {
            p0 = *(const f32x4*)(sSrc + (c + 1) * 128);
            p1 = *(const f32x4*)(sSrc + (c + 1) * 128 + 4);
        }
        const unsigned short* bufp = sX[c & 1];
        const int kbase = c * 128;
#pragma unroll
        for (int kk = 0; kk < 4; ++kk) {
            s16x8 a[4];
#pragma unroll
            for (int mb = 0; mb < 4; ++mb) {
                const int row = mb * 16 + lanelo;
                const int byteoff = row * 256 + ((((kk << 2) + g) ^ (row & 7)) << 4);
                a[mb] = *(const s16x8*)((const char*)bufp + byteoff);
            }
#pragma unroll
            for (int nb = 0; nb < 2; ++nb) {
                const s16x8 bB = *(const s16x8*)(wbRow + (size_t)(nb * 16) * 512 + kbase + kk * 32);
                const s16x8 bE = *(const s16x8*)(weRow + (size_t)(nb * 16) * 512 + kbase + kk * 32);
                __builtin_amdgcn_s_setprio(1);
#pragma unroll
                for (int mb = 0; mb < 4; ++mb) {
                    accB[mb][nb] = __builtin_amdgcn_mfma_f32_16x16x32_bf16(a[mb], bB, accB[mb][nb], 0, 0, 0);
                    accE[mb][nb] = __builtin_amdgcn_mfma_f32_16x16x32_bf16(a[mb], bE, accE[mb][nb], 0, 0, 0);
                }
                __builtin_amdgcn_s_setprio(0);
            }
        }
        if (c < 3) {
            s16x8 hv;
#pragma unroll
            for (int j = 0; j < 4; ++j) { hv[j] = (short)f2b(p0[j]); hv[j + 4] = (short)f2b(p1[j]); }
            *(s16x8*)((char*)sX[(c + 1) & 1] + sDstByte) = hv;
            __syncthreads();
        }
    }

    // ---- epilogue: out = accB + bb' + t.B' + w*(accE + be[e]) ----
    float bbv[2], bev[2], bp[8][2];
#pragma unroll
    for (int nb = 0; nb < 2; ++nb) {
        const int o = colBase + nb * 16 + lanelo;
        bbv[nb] = bbP[o];
        bev[nb] = be[e * 512 + o];
#pragma unroll
        for (int j = 0; j < 8; ++j) bp[j][nb] = BP[j * 512 + o];
    }

#pragma unroll
    for (int mb = 0; mb < 4; ++mb) {
#pragma unroll
        for (int r = 0; r < 4; ++r) {
            const int trow = mb * 16 + g * 4 + r;
            if (trow < mcount) {
                const int tok = perm[e * NTOK + base + trow];
                const float wv = wgt[tok];
                const f32x4 t0 = *(const f32x4*)(tws + (size_t)tok * 8);
                const f32x4 t1 = *(const f32x4*)(tws + (size_t)tok * 8 + 4);
                float* orow = out + (size_t)tok * 512 + colBase + lanelo;
#pragma unroll
                for (int nb = 0; nb < 2; ++nb) {
                    float lora = 0.f;
#pragma unroll
                    for (int j = 0; j < 4; ++j) lora += t0[j] * bp[j][nb];
#pragma unroll
                    for (int j = 0; j < 4; ++j) lora += t1[j] * bp[j + 4][nb];
                    const float v = accB[mb][nb][r] + bbv[nb] + lora
                                  + wv * (accE[mb][nb][r] + bev[nb]);
                    orow[nb * 16] = v;
                }
            }
        }
    }
}

extern "C" void kernel_launch(void* const* d_in, const int* in_sizes, int n_in,
                              void* d_out, int out_size, void* d_ws, size_t ws_size,
                              hipStream_t stream)
{
    const float* x   = (const float*)d_in[0];
    const float* Wb  = (const float*)d_in[1];
    const float* bb  = (const float*)d_in[2];
    const float* A   = (const float*)d_in[3];
    const float* B   = (const float*)d_in[4];
    const float* ia3 = (const float*)d_in[5];
    const float* Wr  = (const float*)d_in[6];
    const float* br  = (const float*)d_in[7];
    const float* We  = (const float*)d_in[8];
    const float* be  = (const float*)d_in[9];
    float* out = (float*)d_out;

    char* w = (char*)d_ws;
    int* cnt            = (int*)w;                              // 256 B
    unsigned short* WbP = (unsigned short*)(w + 256);           // 512*512*2
    unsigned short* WeP = (unsigned short*)(w + 256 + 524288);  // 4*512*512*2
    float* bbP          = (float*)(w + 2621696);                // 512*4
    float* BP           = (float*)(w + 2623744);                // 8*512*4 (pad)
    float* wgt          = (float*)(w + 2640128);                // 65536*4
    float* tws          = (float*)(w + 2902272);                // 65536*8*4
    int* perm           = (int*)(w + 4999424);                  // 4*65536*4

    hipLaunchKernelGGL(prep_kernel, dim3(4096), dim3(256), 0, stream,
                       Wb, bb, B, ia3, We, WbP, WeP, bbP, BP, cnt);
    hipLaunchKernelGGL(router_kernel, dim3(1024), dim3(256), 0, stream,
                       x, A, Wr, br, wgt, tws, perm, cnt);
    hipLaunchKernelGGL(main_kernel, dim3(4096), dim3(1024), 0, stream,
                       x, WbP, WeP, bbP, BP, be, wgt, tws, perm, cnt, out);
}

// Round 3
// 263.641 us; speedup vs baseline: 1.1126x; 1.0745x over previous
//
#include <hip/hip_runtime.h>

typedef __attribute__((ext_vector_type(4))) float f32x4;
typedef __attribute__((ext_vector_type(8))) short s16x8;

#define NTOK 65536
#define KEXT 1088  // 512 x | 512 w*x | 8 t | 1 (bb) | 1 w (be) | 54 zero

__device__ __forceinline__ unsigned short f2b(float f) {
    unsigned int u = __float_as_uint(f);
    u = (u + 0x7FFFu + ((u >> 16) & 1u)) >> 16;
    return (unsigned short)u;
}

__device__ __forceinline__ void gld_lds16(const void* g, void* l) {
    __builtin_amdgcn_global_load_lds(
        (const __attribute__((address_space(1))) unsigned int*)g,
        (__attribute__((address_space(3))) unsigned int*)l, 16, 0, 0);
}

// ---------------- P1: build Wcat[e][512 cols][KEXT] bf16, zero counters ----
__global__ __launch_bounds__(256) void prep_kernel(
    const float* __restrict__ Wb, const float* __restrict__ bb,
    const float* __restrict__ B, const float* __restrict__ ia3,
    const float* __restrict__ We, const float* __restrict__ be,
    unsigned short* __restrict__ Wcat, int* __restrict__ cnt)
{
    int i = blockIdx.x * 256 + threadIdx.x;
    if (i < 4) cnt[i] = 0;
    if (i >= 4 * 512 * KEXT) return;
    const int k = i % KEXT;
    const int r = (i / KEXT) & 511;
    const int e = i / (KEXT * 512);
    float v;
    if (k < 512)        v = Wb[r * 512 + k] * ia3[r];
    else if (k < 1024)  v = We[(e * 512 + r) * 512 + (k - 512)];
    else if (k < 1032)  v = B[(k - 1024) * 512 + r] * 4.0f * ia3[r];
    else if (k == 1032) v = bb[r] * ia3[r];
    else if (k == 1033) v = be[e * 512 + r];
    else                v = 0.0f;
    Wcat[i] = f2b(v);
}

// ---------------- P2: router + LoRA-t + expert compaction -------------------
__global__ __launch_bounds__(256) void router_kernel(
    const float* __restrict__ x, const float* __restrict__ A,
    const float* __restrict__ Wr, const float* __restrict__ br,
    float* __restrict__ wgt, float* __restrict__ tws,
    int* __restrict__ perm, int* __restrict__ cnt)
{
    __shared__ int sCnt[4];
    __shared__ int sBase[4];
    __shared__ int sE[64];
    __shared__ int sPos[64];

    const int tid = threadIdx.x;
    const int wave = tid >> 6, lane = tid & 63;
    const int k0 = lane * 8;

    f32x4 wrv[4][2];
#pragma unroll
    for (int e = 0; e < 4; ++e) {
        wrv[e][0] = *(const f32x4*)(Wr + e * 512 + k0);
        wrv[e][1] = *(const f32x4*)(Wr + e * 512 + k0 + 4);
    }
    f32x4 av[8][2];
#pragma unroll
    for (int j = 0; j < 8; ++j) {
        av[j][0] = *(const f32x4*)(A + (size_t)(k0 + j) * 8);
        av[j][1] = *(const f32x4*)(A + (size_t)(k0 + j) * 8 + 4);
    }
    const float br0 = br[0], br1 = br[1], br2 = br[2], br3 = br[3];

    if (tid < 4) sCnt[tid] = 0;
    __syncthreads();

    const int tok0 = blockIdx.x * 64 + wave * 16;
    for (int it = 0; it < 16; ++it) {
        const int tok = tok0 + it;
        const float* xr = x + (size_t)tok * 512 + k0;
        f32x4 x0 = *(const f32x4*)xr;
        f32x4 x1 = *(const f32x4*)(xr + 4);
        float ar[4] = {0.f, 0.f, 0.f, 0.f};
        float at[8] = {0.f, 0.f, 0.f, 0.f, 0.f, 0.f, 0.f, 0.f};
#pragma unroll
        for (int j = 0; j < 8; ++j) {
            const float xv = (j < 4) ? x0[j] : x1[j - 4];
#pragma unroll
            for (int e = 0; e < 4; ++e) ar[e] += xv * wrv[e][j >> 2][j & 3];
#pragma unroll
            for (int r = 0; r < 8; ++r) at[r] += xv * av[j][r >> 2][r & 3];
        }
#pragma unroll
        for (int off = 32; off >= 1; off >>= 1) {
#pragma unroll
            for (int e = 0; e < 4; ++e) ar[e] += __shfl_xor(ar[e], off);
#pragma unroll
            for (int r = 0; r < 8; ++r) at[r] += __shfl_xor(at[r], off);
        }
        if (lane == 0) {
            const float l0 = ar[0] + br0, l1 = ar[1] + br1;
            const float l2 = ar[2] + br2, l3 = ar[3] + br3;
            int e = 0; float m = l0;
            if (l1 > m) { m = l1; e = 1; }
            if (l2 > m) { m = l2; e = 2; }
            if (l3 > m) { m = l3; e = 3; }
            const float s = expf(l0 - m) + expf(l1 - m) + expf(l2 - m) + expf(l3 - m);
            wgt[tok] = 1.0f / s;  // top value is exp(0)=1
            float* tp = tws + (size_t)tok * 8;
#pragma unroll
            for (int r = 0; r < 8; ++r) tp[r] = at[r];
            const int slot = wave * 16 + it;
            sE[slot] = e;
            sPos[slot] = atomicAdd(&sCnt[e], 1);
        }
    }
    __syncthreads();
    if (tid < 4) sBase[tid] = atomicAdd(&cnt[tid], sCnt[tid]);
    __syncthreads();
    if (tid < 64) {
        const int e = sE[tid];
        perm[e * NTOK + sBase[e] + sPos[tid]] = blockIdx.x * 64 + tid;
    }
}

// ---------------- P3: single fused GEMM, K=1088, B via global_load_lds ------
// block: (e, 64-token tile, 256-col half). 8 waves, wave-tile 64x32, acc=32.
__global__ __launch_bounds__(512) void main_kernel(
    const float* __restrict__ x, const unsigned short* __restrict__ Wcat,
    const float* __restrict__ wgt, const float* __restrict__ tws,
    const int* __restrict__ perm, const int* __restrict__ cnt,
    float* __restrict__ out)
{
    __shared__ unsigned short sA[2][64 * 64];    // 16 KB  (64 rows x 64 k)
    __shared__ unsigned short sB[2][256 * 64];   // 64 KB  (256 cols x 64 k)

    const int e  = blockIdx.x >> 11;
    const int mt = (blockIdx.x >> 1) & 1023;
    const int h  = blockIdx.x & 1;
    const int n = cnt[e];
    const int base = mt * 64;
    if (base >= n) return;
    const int mcount = min(64, n - base);

    const int tid = threadIdx.x;
    const int lane = tid & 63;
    const int wave = tid >> 6;
    const int lanelo = lane & 15;
    const int g = lane >> 4;

    // ---- A staging map: thread -> (row, 16B granule) ----
    const int arow = tid >> 3;
    const int aseg = tid & 7;
    const int atok = perm[e * NTOK + base + min(arow, mcount - 1)];
    const float* axp = x + (size_t)atok * 512 + aseg * 8;
    const float* atp = tws + (size_t)atok * 8;
    const float aw = wgt[atok];
    const int adst = arow * 128 + ((aseg ^ (arow & 7)) << 4);

    // ---- B staging source base (pre-swizzled source, linear LDS dest) ----
    const unsigned short* wcE = Wcat + ((size_t)e * 512 + h * 256) * KEXT;

    // helper lambdas (all c wave-uniform)
    auto issueB = [&](int c, int buf) {
#pragma unroll
        for (int i = 0; i < 4; ++i) {
            const int r = (i * 8 + wave) * 8 + (lane >> 3);
            const unsigned short* src = wcE + (size_t)r * KEXT + c * 64 + (((lane & 7) ^ (r & 7)) << 3);
            gld_lds16(src, (char*)sB[buf] + (i * 8 + wave) * 1024);
        }
    };
    auto loadA = [&](int c, f32x4& p0, f32x4& p1) {
        if (c < 16) {
            p0 = *(const f32x4*)(axp + (c & 7) * 64);
            p1 = *(const f32x4*)(axp + (c & 7) * 64 + 4);
        } else {
            p0 = *(const f32x4*)atp;
            p1 = *(const f32x4*)(atp + 4);
        }
    };
    auto writeA = [&](int c, int buf, f32x4 p0, f32x4 p1) {
        s16x8 hv;
        if (c < 8) {
#pragma unroll
            for (int j = 0; j < 4; ++j) { hv[j] = (short)f2b(p0[j]); hv[j + 4] = (short)f2b(p1[j]); }
        } else if (c < 16) {
#pragma unroll
            for (int j = 0; j < 4; ++j) { hv[j] = (short)f2b(aw * p0[j]); hv[j + 4] = (short)f2b(aw * p1[j]); }
        } else {
            if (aseg == 0) {
#pragma unroll
                for (int j = 0; j < 4; ++j) { hv[j] = (short)f2b(p0[j]); hv[j + 4] = (short)f2b(p1[j]); }
            } else if (aseg == 1) {
#pragma unroll
                for (int j = 0; j < 8; ++j) hv[j] = 0;
                hv[0] = (short)f2b(1.0f);
                hv[1] = (short)f2b(aw);
            } else {
#pragma unroll
                for (int j = 0; j < 8; ++j) hv[j] = 0;
            }
        }
        *(s16x8*)((char*)sA[buf] + adst) = hv;
    };

    // ---- prologue: stage chunk 0 ----
    {
        issueB(0, 0);
        f32x4 p0, p1;
        loadA(0, p0, p1);
        writeA(0, 0, p0, p1);
    }
    __syncthreads();

    f32x4 acc[4][2];
#pragma unroll
    for (int mb = 0; mb < 4; ++mb)
#pragma unroll
        for (int nb = 0; nb < 2; ++nb) acc[mb][nb] = (f32x4){0.f, 0.f, 0.f, 0.f};

    for (int c = 0; c < 17; ++c) {
        const int cur = c & 1, nxt = cur ^ 1;
        f32x4 p0, p1;
        if (c < 16) {
            issueB(c + 1, nxt);
            loadA(c + 1, p0, p1);
        }
        // compute chunk c
        const char* bufA = (const char*)sA[cur];
        const char* bufB = (const char*)sB[cur];
#pragma unroll
        for (int kk = 0; kk < 2; ++kk) {
            s16x8 a[4], b[2];
#pragma unroll
            for (int mb = 0; mb < 4; ++mb) {
                const int row = mb * 16 + lanelo;
                a[mb] = *(const s16x8*)(bufA + row * 128 + ((((kk << 2) + g) ^ (row & 7)) << 4));
            }
#pragma unroll
            for (int nb = 0; nb < 2; ++nb) {
                const int r = wave * 32 + nb * 16 + lanelo;
                b[nb] = *(const s16x8*)(bufB + r * 128 + ((((kk << 2) + g) ^ (r & 7)) << 4));
            }
            __builtin_amdgcn_s_setprio(1);
#pragma unroll
            for (int mb = 0; mb < 4; ++mb)
#pragma unroll
                for (int nb = 0; nb < 2; ++nb)
                    acc[mb][nb] = __builtin_amdgcn_mfma_f32_16x16x32_bf16(a[mb], b[nb], acc[mb][nb], 0, 0, 0);
            __builtin_amdgcn_s_setprio(0);
        }
        if (c < 16) {
            writeA(c + 1, nxt, p0, p1);
            __syncthreads();
        }
    }

    // ---- epilogue: bare scattered store ----
    const int colB = h * 256 + wave * 32 + lanelo;
#pragma unroll
    for (int mb = 0; mb < 4; ++mb)
#pragma unroll
        for (int r4 = 0; r4 < 4; ++r4) {
            const int trow = mb * 16 + g * 4 + r4;
            if (trow < mcount) {
                const int tok = perm[e * NTOK + base + trow];
                float* orow = out + (size_t)tok * 512 + colB;
                orow[0]  = acc[mb][0][r4];
                orow[16] = acc[mb][1][r4];
            }
        }
}

extern "C" void kernel_launch(void* const* d_in, const int* in_sizes, int n_in,
                              void* d_out, int out_size, void* d_ws, size_t ws_size,
                              hipStream_t stream)
{
    const float* x   = (const float*)d_in[0];
    const float* Wb  = (const float*)d_in[1];
    const float* bb  = (const float*)d_in[2];
    const float* A   = (const float*)d_in[3];
    const float* B   = (const float*)d_in[4];
    const float* ia3 = (const float*)d_in[5];
    const float* Wr  = (const float*)d_in[6];
    const float* br  = (const float*)d_in[7];
    const float* We  = (const float*)d_in[8];
    const float* be  = (const float*)d_in[9];
    float* out = (float*)d_out;

    char* w = (char*)d_ws;
    int* cnt             = (int*)w;                      // 256 B
    unsigned short* Wcat = (unsigned short*)(w + 256);   // 4*512*1088*2 = 4456448
    float* wgt           = (float*)(w + 4456704);        // 65536*4
    float* tws           = (float*)(w + 4718848);        // 65536*8*4
    int* perm            = (int*)(w + 6816000);          // 4*65536*4 -> end 7864576

    hipLaunchKernelGGL(prep_kernel, dim3(8704), dim3(256), 0, stream,
                       Wb, bb, B, ia3, We, be, Wcat, cnt);
    hipLaunchKernelGGL(router_kernel, dim3(1024), dim3(256), 0, stream,
                       x, A, Wr, br, wgt, tws, perm, cnt);
    hipLaunchKernelGGL(main_kernel, dim3(8192), dim3(512), 0, stream,
                       x, Wcat, wgt, tws, perm, cnt, out);
}

// Round 4
// 208.155 us; speedup vs baseline: 1.4091x; 1.2666x over previous
//
#include <hip/hip_runtime.h>

typedef __attribute__((ext_vector_type(4))) float f32x4;
typedef __attribute__((ext_vector_type(8))) short s16x8;

#define NTOK 65536
#define KEXT 1088  // 8 pairs of [64 Wb-k | 64 We-k] = 1024, then tail 64

__device__ __forceinline__ unsigned short f2b(float f) {
    unsigned int u = __float_as_uint(f);
    u = (u + 0x7FFFu + ((u >> 16) & 1u)) >> 16;
    return (unsigned short)u;
}

__device__ __forceinline__ void gld_lds16(const void* g, void* l) {
    __builtin_amdgcn_global_load_lds(
        (const __attribute__((address_space(1))) unsigned int*)g,
        (__attribute__((address_space(3))) unsigned int*)l, 16, 0, 0);
}

// ---------------- P1: build Wcat[e][512 cols][KEXT] bf16 (K interleaved) ----
// K pair p (0..7): k = p*128+q ; q<64 -> ia3*Wb col p*64+q ; q>=64 -> We col
// p*64+(q-64). Tail: 1024..1031 = 4*ia3*B rows, 1032 = ia3*bb, 1033 = be.
__global__ __launch_bounds__(256) void prep_kernel(
    const float* __restrict__ Wb, const float* __restrict__ bb,
    const float* __restrict__ B, const float* __restrict__ ia3,
    const float* __restrict__ We, const float* __restrict__ be,
    unsigned short* __restrict__ Wcat, int* __restrict__ cnt)
{
    int i = blockIdx.x * 256 + threadIdx.x;
    if (i < 4) cnt[i] = 0;
    if (i >= 4 * 512 * KEXT) return;
    const int k = i % KEXT;
    const int r = (i / KEXT) & 511;
    const int e = i / (KEXT * 512);
    float v;
    if (k < 1024) {
        const int p = k >> 7, q = k & 127;
        if (q < 64) v = Wb[r * 512 + p * 64 + q] * ia3[r];
        else        v = We[((size_t)e * 512 + r) * 512 + p * 64 + (q - 64)];
    }
    else if (k < 1032)  v = B[(k - 1024) * 512 + r] * 4.0f * ia3[r];
    else if (k == 1032) v = bb[r] * ia3[r];
    else if (k == 1033) v = be[e * 512 + r];
    else                v = 0.0f;
    Wcat[i] = f2b(v);
}

// ---------------- P2: router + LoRA-t + expert compaction -------------------
__global__ __launch_bounds__(256) void router_kernel(
    const float* __restrict__ x, const float* __restrict__ A,
    const float* __restrict__ Wr, const float* __restrict__ br,
    float* __restrict__ wgt, float* __restrict__ tws,
    int* __restrict__ perm, int* __restrict__ cnt)
{
    __shared__ int sCnt[4];
    __shared__ int sBase[4];
    __shared__ int sE[64];
    __shared__ int sPos[64];

    const int tid = threadIdx.x;
    const int wave = tid >> 6, lane = tid & 63;
    const int k0 = lane * 8;

    f32x4 wrv[4][2];
#pragma unroll
    for (int e = 0; e < 4; ++e) {
        wrv[e][0] = *(const f32x4*)(Wr + e * 512 + k0);
        wrv[e][1] = *(const f32x4*)(Wr + e * 512 + k0 + 4);
    }
    f32x4 av[8][2];
#pragma unroll
    for (int j = 0; j < 8; ++j) {
        av[j][0] = *(const f32x4*)(A + (size_t)(k0 + j) * 8);
        av[j][1] = *(const f32x4*)(A + (size_t)(k0 + j) * 8 + 4);
    }
    const float br0 = br[0], br1 = br[1], br2 = br[2], br3 = br[3];

    if (tid < 4) sCnt[tid] = 0;
    __syncthreads();

    const int tok0 = blockIdx.x * 64 + wave * 16;
    for (int it = 0; it < 16; ++it) {
        const int tok = tok0 + it;
        const float* xr = x + (size_t)tok * 512 + k0;
        f32x4 x0 = *(const f32x4*)xr;
        f32x4 x1 = *(const f32x4*)(xr + 4);
        float ar[4] = {0.f, 0.f, 0.f, 0.f};
        float at[8] = {0.f, 0.f, 0.f, 0.f, 0.f, 0.f, 0.f, 0.f};
#pragma unroll
        for (int j = 0; j < 8; ++j) {
            const float xv = (j < 4) ? x0[j] : x1[j - 4];
#pragma unroll
            for (int e = 0; e < 4; ++e) ar[e] += xv * wrv[e][j >> 2][j & 3];
#pragma unroll
            for (int r = 0; r < 8; ++r) at[r] += xv * av[j][r >> 2][r & 3];
        }
#pragma unroll
        for (int off = 32; off >= 1; off >>= 1) {
#pragma unroll
            for (int e = 0; e < 4; ++e) ar[e] += __shfl_xor(ar[e], off);
#pragma unroll
            for (int r = 0; r < 8; ++r) at[r] += __shfl_xor(at[r], off);
        }
        if (lane == 0) {
            const float l0 = ar[0] + br0, l1 = ar[1] + br1;
            const float l2 = ar[2] + br2, l3 = ar[3] + br3;
            int e = 0; float m = l0;
            if (l1 > m) { m = l1; e = 1; }
            if (l2 > m) { m = l2; e = 2; }
            if (l3 > m) { m = l3; e = 3; }
            const float s = expf(l0 - m) + expf(l1 - m) + expf(l2 - m) + expf(l3 - m);
            wgt[tok] = 1.0f / s;  // top value is exp(0)=1
            float* tp = tws + (size_t)tok * 8;
#pragma unroll
            for (int r = 0; r < 8; ++r) tp[r] = at[r];
            const int slot = wave * 16 + it;
            sE[slot] = e;
            sPos[slot] = atomicAdd(&sCnt[e], 1);
        }
    }
    __syncthreads();
    if (tid < 4) sBase[tid] = atomicAdd(&cnt[tid], sCnt[tid]);
    __syncthreads();
    if (tid < 64) {
        const int e = sE[tid];
        perm[e * NTOK + sBase[e] + sPos[tid]] = blockIdx.x * 64 + tid;
    }
}

// ---------------- P3: fused GEMM 128x512xKEXT, XCD-pinned, dbuf LDS ---------
// bid&7 -> xcd: e = xcd>>1, tile parity = xcd&1 -> each expert's Wcat slice
// (1.1 MB) stays L2-resident on its 2 XCDs. 16 waves, wave-tile 64x64.
__global__ __launch_bounds__(1024) void main_kernel(
    const float* __restrict__ x, const unsigned short* __restrict__ Wcat,
    const float* __restrict__ wgt, const float* __restrict__ tws,
    const int* __restrict__ perm, const int* __restrict__ cnt,
    float* __restrict__ out)
{
    __shared__ unsigned short sA[2][128 * 64];   // 2 x 16 KB
    __shared__ unsigned short sB[2][512 * 64];   // 2 x 64 KB  (total 160 KB)

    const int bid = blockIdx.x;
    const int xcd = bid & 7;
    const int e = xcd >> 1;
    const int tile = ((bid >> 3) << 1) + (xcd & 1);
    const int n = cnt[e];
    const int base = tile * 128;
    if (base >= n) return;
    const int mcount = min(128, n - base);

    const int tid = threadIdx.x;
    const int lane = tid & 63;
    const int wave = tid >> 6;        // 0..15
    const int lanelo = lane & 15;
    const int g = lane >> 4;          // 0..3
    const int mw = wave >> 3;         // 0..1
    const int nw = wave & 7;          // 0..7

    // ---- A staging map: thread -> (arow, aseg) ----
    const int arow = tid >> 3;        // 0..127
    const int aseg = tid & 7;         // 0..7
    const int atok = perm[e * NTOK + base + min(arow, mcount - 1)];
    const float* axp = x + (size_t)atok * 512 + aseg * 8;
    const float* atp = tws + (size_t)atok * 8;
    const float aw = wgt[atok];
    const int adst = arow * 128 + ((aseg ^ (arow & 7)) << 4);   // bytes

    // ---- B staging: 4 gld groups per wave, pre-swizzled source ----
    const unsigned short* wcE = Wcat + (size_t)e * 512 * KEXT;
    const unsigned short* bsrc[4];
    int bdst[4];
#pragma unroll
    for (int i = 0; i < 4; ++i) {
        const int gi = i * 16 + wave;             // 0..63 row-groups of 8
        const int wr = gi * 8 + (lane >> 3);      // weight row (= out col)
        const int G = (lane & 7) ^ (wr & 7);      // swizzled source granule
        bsrc[i] = wcE + (size_t)wr * KEXT + G * 8;
        bdst[i] = gi * 1024;                      // linear LDS dest, bytes
    }

    f32x4 p0, p1;   // persistent staging regs (x pair reused for odd chunks)
    auto loadA = [&](int ch) {
        if (ch == 16)      { p0 = *(const f32x4*)atp; p1 = *(const f32x4*)(atp + 4); }
        else if (!(ch & 1)) {
            p0 = *(const f32x4*)(axp + (ch >> 1) * 64);
            p1 = *(const f32x4*)(axp + (ch >> 1) * 64 + 4);
        }
    };
    auto writeA = [&](int ch, int buf) {
        s16x8 hv;
        if (ch == 16) {
#pragma unroll
            for (int j = 0; j < 8; ++j) hv[j] = 0;
            if (aseg == 0) {
#pragma unroll
                for (int j = 0; j < 4; ++j) { hv[j] = (short)f2b(p0[j]); hv[j + 4] = (short)f2b(p1[j]); }
            } else if (aseg == 1) {
                hv[0] = (short)f2b(1.0f);
                hv[1] = (short)f2b(aw);
            }
        } else {
            const float s = (ch & 1) ? aw : 1.0f;
#pragma unroll
            for (int j = 0; j < 4; ++j) { hv[j] = (short)f2b(s * p0[j]); hv[j + 4] = (short)f2b(s * p1[j]); }
        }
        *(s16x8*)((char*)sA[buf] + adst) = hv;
    };
    auto issueB = [&](int ch, int buf) {
#pragma unroll
        for (int i = 0; i < 4; ++i)
            gld_lds16(bsrc[i] + ch * 64, (char*)sB[buf] + bdst[i]);
    };

    // ---- prologue: stage chunk 0 ----
    loadA(0);
    issueB(0, 0);
    writeA(0, 0);
    __syncthreads();

    f32x4 acc[4][4];
#pragma unroll
    for (int mb = 0; mb < 4; ++mb)
#pragma unroll
        for (int nb = 0; nb < 4; ++nb) acc[mb][nb] = (f32x4){0.f, 0.f, 0.f, 0.f};

    for (int c = 0; c < 17; ++c) {
        const int cur = c & 1, nxt = cur ^ 1;
        if (c < 16) {
            loadA(c + 1);       // T14: global issue early (even/tail only)
            issueB(c + 1, nxt); // fire-and-forget into other buffer
        }
        const char* bufA = (const char*)sA[cur];
        const char* bufB = (const char*)sB[cur];
#pragma unroll
        for (int kk = 0; kk < 2; ++kk) {
            s16x8 a[4];
#pragma unroll
            for (int mb = 0; mb < 4; ++mb) {
                const int row = mw * 64 + mb * 16 + lanelo;
                a[mb] = *(const s16x8*)(bufA + row * 128 + ((((kk << 2) + g) ^ (row & 7)) << 4));
            }
#pragma unroll
            for (int nb = 0; nb < 4; ++nb) {
                const int wr = nw * 64 + nb * 16 + lanelo;
                const s16x8 b = *(const s16x8*)(bufB + wr * 128 + ((((kk << 2) + g) ^ (wr & 7)) << 4));
                __builtin_amdgcn_s_setprio(1);
#pragma unroll
                for (int mb = 0; mb < 4; ++mb)
                    acc[mb][nb] = __builtin_amdgcn_mfma_f32_16x16x32_bf16(a[mb], b, acc[mb][nb], 0, 0, 0);
                __builtin_amdgcn_s_setprio(0);
            }
        }
        if (c < 16) {
            writeA(c + 1, nxt);
            __syncthreads();    // drains vmcnt (B chunk c+1 landed) + lgkm
        }
    }

    // ---- epilogue: bare scattered store ----
    const int col0 = nw * 64 + lanelo;
#pragma unroll
    for (int mb = 0; mb < 4; ++mb) {
#pragma unroll
        for (int r = 0; r < 4; ++r) {
            const int trow = mw * 64 + mb * 16 + g * 4 + r;
            if (trow < mcount) {
                const int tok = perm[e * NTOK + base + trow];
                float* orow = out + (size_t)tok * 512 + col0;
                orow[0]  = acc[mb][0][r];
                orow[16] = acc[mb][1][r];
                orow[32] = acc[mb][2][r];
                orow[48] = acc[mb][3][r];
            }
        }
    }
}

extern "C" void kernel_launch(void* const* d_in, const int* in_sizes, int n_in,
                              void* d_out, int out_size, void* d_ws, size_t ws_size,
                              hipStream_t stream)
{
    const float* x   = (const float*)d_in[0];
    const float* Wb  = (const float*)d_in[1];
    const float* bb  = (const float*)d_in[2];
    const float* A   = (const float*)d_in[3];
    const float* B   = (const float*)d_in[4];
    const float* ia3 = (const float*)d_in[5];
    const float* Wr  = (const float*)d_in[6];
    const float* br  = (const float*)d_in[7];
    const float* We  = (const float*)d_in[8];
    const float* be  = (const float*)d_in[9];
    float* out = (float*)d_out;

    char* w = (char*)d_ws;
    int* cnt             = (int*)w;                      // 256 B
    unsigned short* Wcat = (unsigned short*)(w + 256);   // 4*512*1088*2 = 4456448
    float* wgt           = (float*)(w + 4456704);        // 65536*4
    float* tws           = (float*)(w + 4718848);        // 65536*8*4
    int* perm            = (int*)(w + 6816000);          // 4*65536*4 -> end 7864576

    hipLaunchKernelGGL(prep_kernel, dim3(8704), dim3(256), 0, stream,
                       Wb, bb, B, ia3, We, be, Wcat, cnt);
    hipLaunchKernelGGL(router_kernel, dim3(1024), dim3(256), 0, stream,
                       x, A, Wr, br, wgt, tws, perm, cnt);
    hipLaunchKernelGGL(main_kernel, dim3(2048), dim3(1024), 0, stream,
                       x, Wcat, wgt, tws, perm, cnt, out);
}